// Round 6
// baseline (259.491 us; speedup 1.0000x reference)
//
#include <hip/hip_runtime.h>

// Problem constants: B=8, L=64, D=768, H=12, d=64
#define DMODEL 768
#define NHEADS 12
#define RTOT   512           // B*L rows
#define BIW    9216          // NHEADS*DMODEL (per-(b,i) u/w row)

// ---------------------------------------------------------------------------
// 16x32-tile fp32 GEMM, register-double-buffered K chunks of 64.
// dst[r, ct*32+c] = (sum_k src[r*ars + sk + k]*W[k, ct*32+c] + bias)*scale
// grid = (32, 24), 256 threads
// ---------------------------------------------------------------------------
__global__ __launch_bounds__(256) void linear16(
    const float* __restrict__ src, int ars, int scm,
    const float* __restrict__ W, const float* __restrict__ bias,
    float* __restrict__ dst, int drs, float scale)
{
    __shared__ float At[16][64];   // 4 KB
    __shared__ float Bt[64][32];   // 8 KB
    const int rt = blockIdx.x, ct = blockIdx.y, t = threadIdx.x;
    const int sk = ((ct * 32) >> 6) * scm;
    const int c  = t & 31;
    const int rg = t >> 5;             // 8 groups x 2 rows

    const int ar0 = t >> 4,          ak0 = t & 15;          // 1 float4 A
    const int bk0 = t >> 3,          bc0 = (t & 7) * 4;     // 2 float4 B
    const int bk1 = (t + 256) >> 3,  bc1 = ((t + 256) & 7) * 4;

    float4 va0, vb0, vb1;
    auto LD = [&](int kb) {
        va0 = *(const float4*)&src[(size_t)(rt * 16 + ar0) * ars + sk + kb * 64 + ak0 * 4];
        vb0 = *(const float4*)&W[(size_t)(kb * 64 + bk0) * DMODEL + ct * 32 + bc0];
        vb1 = *(const float4*)&W[(size_t)(kb * 64 + bk1) * DMODEL + ct * 32 + bc1];
    };

    LD(0);
    float acc[2] = {0.f, 0.f};

    for (int kb = 0; kb < 12; ++kb) {
        if (kb) __syncthreads();
        *(float4*)&At[ar0][ak0 * 4] = va0;
        *(float4*)&Bt[bk0][bc0] = vb0;
        *(float4*)&Bt[bk1][bc1] = vb1;
        __syncthreads();
        if (kb < 11) LD(kb + 1);
        #pragma unroll
        for (int kq = 0; kq < 16; ++kq) {
            float b0 = Bt[kq * 4 + 0][c], b1 = Bt[kq * 4 + 1][c];
            float b2 = Bt[kq * 4 + 2][c], b3 = Bt[kq * 4 + 3][c];
            #pragma unroll
            for (int i = 0; i < 2; ++i) {
                float4 a = *(const float4*)&At[rg * 2 + i][kq * 4];
                acc[i] += a.x * b0 + a.y * b1 + a.z * b2 + a.w * b3;
            }
        }
    }
    const float bb = bias[ct * 32 + c];
    #pragma unroll
    for (int i = 0; i < 2; ++i)
        dst[(size_t)(rt * 16 + rg * 2 + i) * drs + ct * 32 + c] = (acc[i] + bb) * scale;
}

// ---------------------------------------------------------------------------
// u[r, h, m] = sum_d Qp[r, h*64+d] * Wk[m, h*64+d];  cvec[r,h] = sum_d bk[h*64+d]*Qp[r,h*64+d]
// grid = (16, 12, 12), 256 threads
// ---------------------------------------------------------------------------
__global__ __launch_bounds__(256) void u_kernel(
    const float* __restrict__ qp, const float* __restrict__ Wk, const float* __restrict__ bk,
    float* __restrict__ u, float* __restrict__ cvec)
{
    __shared__ float Qt[32][64];    // 8 KB
    __shared__ float Bt[64][65];    // 16.25 KB (pad -> conflict-free b32 row reads)
    const int rt = blockIdx.x, mt = blockIdx.y, h = blockIdx.z, t = threadIdx.x;

    #pragma unroll
    for (int kk = 0; kk < 2; ++kk) {
        int i4 = t + kk * 256;
        int r = i4 >> 4, dq = i4 & 15;
        *(float4*)&Qt[r][dq * 4] =
            *(const float4*)&qp[(size_t)(rt * 32 + r) * DMODEL + h * 64 + dq * 4];
    }
    #pragma unroll
    for (int kk = 0; kk < 4; ++kk) {
        int i4 = t + kk * 256;
        int m = i4 >> 4, dq = i4 & 15;
        float4 v = *(const float4*)&Wk[(size_t)(mt * 64 + m) * DMODEL + h * 64 + dq * 4];
        Bt[m][dq * 4 + 0] = v.x; Bt[m][dq * 4 + 1] = v.y;
        Bt[m][dq * 4 + 2] = v.z; Bt[m][dq * 4 + 3] = v.w;
    }
    __syncthreads();

    const int c = t & 63, rg = t >> 6;
    float acc[8] = {0.f,0.f,0.f,0.f,0.f,0.f,0.f,0.f};
    #pragma unroll
    for (int dq = 0; dq < 16; ++dq) {
        float b0 = Bt[c][dq * 4 + 0], b1 = Bt[c][dq * 4 + 1];
        float b2 = Bt[c][dq * 4 + 2], b3 = Bt[c][dq * 4 + 3];
        #pragma unroll
        for (int i = 0; i < 8; ++i) {
            float4 a = *(const float4*)&Qt[rg * 8 + i][dq * 4];
            acc[i] += a.x * b0 + a.y * b1 + a.z * b2 + a.w * b3;
        }
    }
    #pragma unroll
    for (int i = 0; i < 8; ++i)
        u[(size_t)(rt * 32 + rg * 8 + i) * BIW + h * DMODEL + mt * 64 + c] = acc[i];

    if (mt == 0 && t < 32) {
        float s = 0.f;
        for (int d = 0; d < 64; ++d) s += bk[h * 64 + d] * Qt[t][d];
        cvec[(rt * 32 + t) * NHEADS + h] = s;
    }
}

// ---------------------------------------------------------------------------
// Core: per (b,i) block, 1024 threads (16 waves) -> 2 blocks/CU, up to 100% occ.
// Phase 1: wave wv owns rows j = wv*4..+4 (one pass), coalesced key stream,
//          depth-1 prefetch, u in LDS, 30-shfl split-tree.
// Softmax: wave wv -> head wv (waves 12..15 idle).
// Phase 3: four 256-thread groups, group hp owns heads hp*3..+3, all 64 j;
//          duplicate value loads are same-address -> L1 broadcast.
// ---------------------------------------------------------------------------
__global__ __launch_bounds__(1024, 4) void attn_core(
    const float* __restrict__ key, const float* __restrict__ value, const float* __restrict__ mask,
    const float* __restrict__ u, const float* __restrict__ cvec, float* __restrict__ w)
{
    __shared__ float u_sh[NHEADS * DMODEL];   // 36 KB
    __shared__ float sc[NHEADS][66];          // scores -> attn in place

    const int bi   = blockIdx.x;
    const int t    = threadIdx.x;
    const int lane = t & 63;
    const int wv   = t >> 6;                  // wave 0..15
    const size_t kvb = (size_t)bi * 64 * DMODEL;

    // stage u[bi] (36 KB = 9216 float4), coalesced: 9 float4 per thread
    #pragma unroll
    for (int kk = 0; kk < 9; ++kk) {
        int idx = (t + kk * 1024) * 4;
        *(float4*)&u_sh[idx] = *(const float4*)&u[(size_t)bi * BIW + idx];
    }
    __syncthreads();

    // ---- phase 1: wave wv owns rows j0..j0+3
    {
        const int j0 = wv * 4;
        float a[NHEADS][4];
        #pragma unroll
        for (int h = 0; h < NHEADS; ++h)
            #pragma unroll
            for (int r = 0; r < 4; ++r) a[h][r] = 0.f;

        float4 kc[4], kn[4];
        #pragma unroll
        for (int r = 0; r < 4; ++r)
            kc[r] = *(const float4*)&key[kvb + (size_t)(j0 + r) * DMODEL + lane * 4];

        #pragma unroll
        for (int cch = 0; cch < 3; ++cch) {
            if (cch < 2) {
                #pragma unroll
                for (int r = 0; r < 4; ++r)
                    kn[r] = *(const float4*)&key[kvb + (size_t)(j0 + r) * DMODEL + (cch + 1) * 256 + lane * 4];
            }
            #pragma unroll
            for (int h = 0; h < NHEADS; ++h) {
                float4 u4 = *(const float4*)&u_sh[h * DMODEL + cch * 256 + lane * 4];
                #pragma unroll
                for (int r = 0; r < 4; ++r)
                    a[h][r] += kc[r].x * u4.x + kc[r].y * u4.y + kc[r].z * u4.z + kc[r].w * u4.w;
            }
            #pragma unroll
            for (int r = 0; r < 4; ++r) kc[r] = kn[r];
        }

        // split-tree reduce: 12 heads over 64 lanes -> 30 shfl per row
        #pragma unroll
        for (int r = 0; r < 4; ++r) {
            float s6[6];
            #pragma unroll
            for (int i = 0; i < 6; ++i) {
                float lo = a[i][r], hi = a[i + 6][r];
                float tl = __shfl_xor(lo, 32), th = __shfl_xor(hi, 32);
                s6[i] = (lane < 32) ? lo + tl : hi + th;
            }
            float s3[3];
            #pragma unroll
            for (int i = 0; i < 3; ++i) {
                float lo = s6[i], hi = s6[i + 3];
                float tl = __shfl_xor(lo, 16), th = __shfl_xor(hi, 16);
                s3[i] = ((lane & 16) == 0) ? lo + tl : hi + th;
            }
            #pragma unroll
            for (int o = 8; o >= 1; o >>= 1)
                #pragma unroll
                for (int i = 0; i < 3; ++i) s3[i] += __shfl_xor(s3[i], o);
            if ((lane & 15) == 0) {
                const int g = lane >> 4;
                #pragma unroll
                for (int i = 0; i < 3; ++i) sc[g * 3 + i][j0 + r] = s3[i];
            }
        }
    }
    __syncthreads();

    // ---- softmax: wave wv -> head wv (waves 12..15 idle)
    if (wv < NHEADS) {
        const int h = wv;
        const float mk = mask[bi * 64 + lane];
        float s = (sc[h][lane] + cvec[bi * NHEADS + h]) * mk;
        float mx = s;
        #pragma unroll
        for (int o = 1; o < 64; o <<= 1) mx = fmaxf(mx, __shfl_xor(mx, o));
        float e = __expf(s - mx);
        float sm = e;
        #pragma unroll
        for (int o = 1; o < 64; o <<= 1) sm += __shfl_xor(sm, o);
        sc[h][lane] = e / sm;
    }
    __syncthreads();

    // ---- phase 3: group hp = t>>8 owns heads hp*3..+3; m = mo + {0,256,512}
    {
        const int hp = t >> 8, mo = t & 255;
        const int h0 = hp * 3;
        float a3[3][3];
        #pragma unroll
        for (int hh = 0; hh < 3; ++hh) { a3[hh][0] = 0.f; a3[hh][1] = 0.f; a3[hh][2] = 0.f; }
        const float* vb = value + kvb + mo;
        #pragma unroll 4
        for (int j = 0; j < 64; ++j) {
            float v0 = vb[(size_t)j * DMODEL];
            float v1 = vb[(size_t)j * DMODEL + 256];
            float v2 = vb[(size_t)j * DMODEL + 512];
            #pragma unroll
            for (int hh = 0; hh < 3; ++hh) {
                float av = sc[h0 + hh][j];
                a3[hh][0] += av * v0;
                a3[hh][1] += av * v1;
                a3[hh][2] += av * v2;
            }
        }
        #pragma unroll
        for (int hh = 0; hh < 3; ++hh)
            #pragma unroll
            for (int mm = 0; mm < 3; ++mm)
                w[(size_t)bi * BIW + (h0 + hh) * DMODEL + mo + mm * 256] = a3[hh][mm];
    }
}

// ---------------------------------------------------------------------------
extern "C" void kernel_launch(void* const* d_in, const int* in_sizes, int n_in,
                              void* d_out, int out_size, void* d_ws, size_t ws_size,
                              hipStream_t stream) {
    const float* key   = (const float*)d_in[0];
    const float* value = (const float*)d_in[1];
    const float* query = (const float*)d_in[2];
    const float* mask  = (const float*)d_in[3];
    const float* Wk    = (const float*)d_in[4];
    const float* bk    = (const float*)d_in[5];
    const float* Wv    = (const float*)d_in[6];
    const float* bv    = (const float*)d_in[7];
    const float* Wq    = (const float*)d_in[8];
    const float* bq    = (const float*)d_in[9];
    const float* Wo    = (const float*)d_in[10];
    const float* bo    = (const float*)d_in[11];
    float* out = (float*)d_out;

    float* wsf    = (float*)d_ws;
    float* qp_ctx = wsf;                                // 512*768 (Qp, later ctx)
    float* u_w    = wsf + (size_t)RTOT * DMODEL;        // 512*9216 (u, later w)
    float* cvec   = u_w + (size_t)RTOT * BIW;           // 512*12

    // 1. Qp = (query @ Wq + bq) / 8
    linear16<<<dim3(32, 24), 256, 0, stream>>>(query, DMODEL, 0, Wq, bq, qp_ctx, DMODEL, 0.125f);
    // 2. u[r,h,m], cvec[r,h]
    u_kernel<<<dim3(16, 12, 12), 256, 0, stream>>>(qp_ctx, Wk, bk, u_w, cvec);
    // 3. scores/softmax/w  (w overwrites u region; u staged to LDS before w writes)
    attn_core<<<512, 1024, 0, stream>>>(key, value, mask, u_w, cvec, u_w);
    // 4. ctx[r, h*64+cc] = w[r,h,:] @ Wv[:, h*64+cc] + bv
    linear16<<<dim3(32, 24), 256, 0, stream>>>(u_w, BIW, DMODEL, Wv, bv, qp_ctx, DMODEL, 1.0f);
    // 5. out = ctx @ Wo + bo
    linear16<<<dim3(32, 24), 256, 0, stream>>>(qp_ctx, DMODEL, 0, Wo, bo, out, DMODEL, 1.0f);
}

// Round 7
// 238.731 us; speedup vs baseline: 1.0870x; 1.0870x over previous
//
#include <hip/hip_runtime.h>

// Problem constants: B=8, L=64, D=768, H=12, d=64
#define DMODEL 768
#define NHEADS 12
#define RTOT   512           // B*L rows
#define BIW    9216          // NHEADS*DMODEL (per-(b,i) u/w row)

// ---------------------------------------------------------------------------
// 16x32-tile fp32 GEMM, register-double-buffered K chunks of 64.
// grid = (32, 24), 256 threads
// ---------------------------------------------------------------------------
__global__ __launch_bounds__(256) void linear16(
    const float* __restrict__ src, int ars, int scm,
    const float* __restrict__ W, const float* __restrict__ bias,
    float* __restrict__ dst, int drs, float scale)
{
    __shared__ float At[16][64];   // 4 KB
    __shared__ float Bt[64][32];   // 8 KB
    const int rt = blockIdx.x, ct = blockIdx.y, t = threadIdx.x;
    const int sk = ((ct * 32) >> 6) * scm;
    const int c  = t & 31;
    const int rg = t >> 5;             // 8 groups x 2 rows

    const int ar0 = t >> 4,          ak0 = t & 15;          // 1 float4 A
    const int bk0 = t >> 3,          bc0 = (t & 7) * 4;     // 2 float4 B
    const int bk1 = (t + 256) >> 3,  bc1 = ((t + 256) & 7) * 4;

    float4 va0, vb0, vb1;
    auto LD = [&](int kb) {
        va0 = *(const float4*)&src[(size_t)(rt * 16 + ar0) * ars + sk + kb * 64 + ak0 * 4];
        vb0 = *(const float4*)&W[(size_t)(kb * 64 + bk0) * DMODEL + ct * 32 + bc0];
        vb1 = *(const float4*)&W[(size_t)(kb * 64 + bk1) * DMODEL + ct * 32 + bc1];
    };

    LD(0);
    float acc[2] = {0.f, 0.f};

    for (int kb = 0; kb < 12; ++kb) {
        if (kb) __syncthreads();
        *(float4*)&At[ar0][ak0 * 4] = va0;
        *(float4*)&Bt[bk0][bc0] = vb0;
        *(float4*)&Bt[bk1][bc1] = vb1;
        __syncthreads();
        if (kb < 11) LD(kb + 1);
        #pragma unroll
        for (int kq = 0; kq < 16; ++kq) {
            float b0 = Bt[kq * 4 + 0][c], b1 = Bt[kq * 4 + 1][c];
            float b2 = Bt[kq * 4 + 2][c], b3 = Bt[kq * 4 + 3][c];
            #pragma unroll
            for (int i = 0; i < 2; ++i) {
                float4 a = *(const float4*)&At[rg * 2 + i][kq * 4];
                acc[i] += a.x * b0 + a.y * b1 + a.z * b2 + a.w * b3;
            }
        }
    }
    const float bb = bias[ct * 32 + c];
    #pragma unroll
    for (int i = 0; i < 2; ++i)
        dst[(size_t)(rt * 16 + rg * 2 + i) * drs + ct * 32 + c] = (acc[i] + bb) * scale;
}

// ---------------------------------------------------------------------------
// u[r, h, m] = sum_d Qp[r, h*64+d] * Wk[m, h*64+d];  cvec[r,h] = sum_d bk[h*64+d]*Qp[r,h*64+d]
// grid = (16, 12, 12), 256 threads
// ---------------------------------------------------------------------------
__global__ __launch_bounds__(256) void u_kernel(
    const float* __restrict__ qp, const float* __restrict__ Wk, const float* __restrict__ bk,
    float* __restrict__ u, float* __restrict__ cvec)
{
    __shared__ float Qt[32][64];    // 8 KB
    __shared__ float Bt[64][65];    // 16.25 KB (pad -> conflict-free b32 row reads)
    const int rt = blockIdx.x, mt = blockIdx.y, h = blockIdx.z, t = threadIdx.x;

    #pragma unroll
    for (int kk = 0; kk < 2; ++kk) {
        int i4 = t + kk * 256;
        int r = i4 >> 4, dq = i4 & 15;
        *(float4*)&Qt[r][dq * 4] =
            *(const float4*)&qp[(size_t)(rt * 32 + r) * DMODEL + h * 64 + dq * 4];
    }
    #pragma unroll
    for (int kk = 0; kk < 4; ++kk) {
        int i4 = t + kk * 256;
        int m = i4 >> 4, dq = i4 & 15;
        float4 v = *(const float4*)&Wk[(size_t)(mt * 64 + m) * DMODEL + h * 64 + dq * 4];
        Bt[m][dq * 4 + 0] = v.x; Bt[m][dq * 4 + 1] = v.y;
        Bt[m][dq * 4 + 2] = v.z; Bt[m][dq * 4 + 3] = v.w;
    }
    __syncthreads();

    const int c = t & 63, rg = t >> 6;
    float acc[8] = {0.f,0.f,0.f,0.f,0.f,0.f,0.f,0.f};
    #pragma unroll
    for (int dq = 0; dq < 16; ++dq) {
        float b0 = Bt[c][dq * 4 + 0], b1 = Bt[c][dq * 4 + 1];
        float b2 = Bt[c][dq * 4 + 2], b3 = Bt[c][dq * 4 + 3];
        #pragma unroll
        for (int i = 0; i < 8; ++i) {
            float4 a = *(const float4*)&Qt[rg * 8 + i][dq * 4];
            acc[i] += a.x * b0 + a.y * b1 + a.z * b2 + a.w * b3;
        }
    }
    #pragma unroll
    for (int i = 0; i < 8; ++i)
        u[(size_t)(rt * 32 + rg * 8 + i) * BIW + h * DMODEL + mt * 64 + c] = acc[i];

    if (mt == 0 && t < 32) {
        float s = 0.f;
        for (int d = 0; d < 64; ++d) s += bk[h * 64 + d] * Qt[t][d];
        cvec[(rt * 32 + t) * NHEADS + h] = s;
    }
}

// ---------------------------------------------------------------------------
// Core: per (b,i) block, 1024 threads (16 waves).
// __launch_bounds__(1024,2): 2 blocks/CU = 32 waves/CU target -> VGPR cap 64.
// Phase 1 restructured for <=64 VGPR: wave owns 2 rows per pass, 2 passes
// (a[12][2]=24 + kc/kn[2]=16 floats live). Coalesced key stream, depth-1
// chunk prefetch, u in LDS, split-tree reduce.
// Softmax: wave wv -> head wv (waves 12..15 idle).
// Phase 3: four 256-thread groups x 3 heads, same-address value loads
// dedupe in L1/L2.
// ---------------------------------------------------------------------------
__global__ __launch_bounds__(1024, 2) void attn_core(
    const float* __restrict__ key, const float* __restrict__ value, const float* __restrict__ mask,
    const float* __restrict__ u, const float* __restrict__ cvec, float* __restrict__ w)
{
    __shared__ float u_sh[NHEADS * DMODEL];   // 36 KB
    __shared__ float sc[NHEADS][66];          // scores -> attn in place

    const int bi   = blockIdx.x;
    const int t    = threadIdx.x;
    const int lane = t & 63;
    const int wv   = t >> 6;                  // wave 0..15
    const size_t kvb = (size_t)bi * 64 * DMODEL;

    // stage u[bi] (2304 float4), coalesced
    #pragma unroll
    for (int kk = 0; kk < 3; ++kk) {
        int i4 = t + kk * 1024;
        if (i4 < 2304)
            *(float4*)&u_sh[i4 * 4] = *(const float4*)&u[(size_t)bi * BIW + i4 * 4];
    }
    __syncthreads();

    // ---- phase 1: wave wv owns rows {wv*2, wv*2+1} then {+32}
    #pragma unroll
    for (int rb = 0; rb < 2; ++rb) {
        const int j0 = rb * 32 + wv * 2;
        float a[NHEADS][2];
        #pragma unroll
        for (int h = 0; h < NHEADS; ++h) { a[h][0] = 0.f; a[h][1] = 0.f; }

        const float* k0 = &key[kvb + (size_t)j0 * DMODEL + lane * 4];
        float4 kc[2], kn[2];
        kc[0] = *(const float4*)k0;
        kc[1] = *(const float4*)(k0 + DMODEL);

        #pragma unroll
        for (int cch = 0; cch < 3; ++cch) {
            if (cch < 2) {
                kn[0] = *(const float4*)(k0 + (cch + 1) * 256);
                kn[1] = *(const float4*)(k0 + DMODEL + (cch + 1) * 256);
            }
            #pragma unroll
            for (int h = 0; h < NHEADS; ++h) {
                float4 u4 = *(const float4*)&u_sh[h * DMODEL + cch * 256 + lane * 4];
                a[h][0] += kc[0].x * u4.x + kc[0].y * u4.y + kc[0].z * u4.z + kc[0].w * u4.w;
                a[h][1] += kc[1].x * u4.x + kc[1].y * u4.y + kc[1].z * u4.z + kc[1].w * u4.w;
            }
            kc[0] = kn[0];
            kc[1] = kn[1];
        }

        // split-tree reduce: 12 heads over 64 lanes -> 15 shfl-stages per row
        #pragma unroll
        for (int r = 0; r < 2; ++r) {
            float s6[6];
            #pragma unroll
            for (int i = 0; i < 6; ++i) {
                float lo = a[i][r], hi = a[i + 6][r];
                float tl = __shfl_xor(lo, 32), th = __shfl_xor(hi, 32);
                s6[i] = (lane < 32) ? lo + tl : hi + th;
            }
            float s3[3];
            #pragma unroll
            for (int i = 0; i < 3; ++i) {
                float lo = s6[i], hi = s6[i + 3];
                float tl = __shfl_xor(lo, 16), th = __shfl_xor(hi, 16);
                s3[i] = ((lane & 16) == 0) ? lo + tl : hi + th;
            }
            #pragma unroll
            for (int o = 8; o >= 1; o >>= 1)
                #pragma unroll
                for (int i = 0; i < 3; ++i) s3[i] += __shfl_xor(s3[i], o);
            if ((lane & 15) == 0) {
                const int g = lane >> 4;
                #pragma unroll
                for (int i = 0; i < 3; ++i) sc[g * 3 + i][j0 + r] = s3[i];
            }
        }
    }
    __syncthreads();

    // ---- softmax: wave wv -> head wv (waves 12..15 idle)
    if (wv < NHEADS) {
        const int h = wv;
        const float mk = mask[bi * 64 + lane];
        float s = (sc[h][lane] + cvec[bi * NHEADS + h]) * mk;
        float mx = s;
        #pragma unroll
        for (int o = 1; o < 64; o <<= 1) mx = fmaxf(mx, __shfl_xor(mx, o));
        float e = __expf(s - mx);
        float sm = e;
        #pragma unroll
        for (int o = 1; o < 64; o <<= 1) sm += __shfl_xor(sm, o);
        sc[h][lane] = e / sm;
    }
    __syncthreads();

    // ---- phase 3: group hp = t>>8 owns heads hp*3..+3; m = mo + {0,256,512}
    {
        const int hp = t >> 8, mo = t & 255;
        const int h0 = hp * 3;
        float a3[3][3];
        #pragma unroll
        for (int hh = 0; hh < 3; ++hh) { a3[hh][0] = 0.f; a3[hh][1] = 0.f; a3[hh][2] = 0.f; }
        const float* vb = value + kvb + mo;
        #pragma unroll 4
        for (int j = 0; j < 64; ++j) {
            float v0 = vb[(size_t)j * DMODEL];
            float v1 = vb[(size_t)j * DMODEL + 256];
            float v2 = vb[(size_t)j * DMODEL + 512];
            #pragma unroll
            for (int hh = 0; hh < 3; ++hh) {
                float av = sc[h0 + hh][j];
                a3[hh][0] += av * v0;
                a3[hh][1] += av * v1;
                a3[hh][2] += av * v2;
            }
        }
        #pragma unroll
        for (int hh = 0; hh < 3; ++hh)
            #pragma unroll
            for (int mm = 0; mm < 3; ++mm)
                w[(size_t)bi * BIW + (h0 + hh) * DMODEL + mo + mm * 256] = a3[hh][mm];
    }
}

// ---------------------------------------------------------------------------
extern "C" void kernel_launch(void* const* d_in, const int* in_sizes, int n_in,
                              void* d_out, int out_size, void* d_ws, size_t ws_size,
                              hipStream_t stream) {
    const float* key   = (const float*)d_in[0];
    const float* value = (const float*)d_in[1];
    const float* query = (const float*)d_in[2];
    const float* mask  = (const float*)d_in[3];
    const float* Wk    = (const float*)d_in[4];
    const float* bk    = (const float*)d_in[5];
    const float* Wv    = (const float*)d_in[6];
    const float* bv    = (const float*)d_in[7];
    const float* Wq    = (const float*)d_in[8];
    const float* bq    = (const float*)d_in[9];
    const float* Wo    = (const float*)d_in[10];
    const float* bo    = (const float*)d_in[11];
    float* out = (float*)d_out;

    float* wsf    = (float*)d_ws;
    float* qp_ctx = wsf;                                // 512*768 (Qp, later ctx)
    float* u_w    = wsf + (size_t)RTOT * DMODEL;        // 512*9216 (u, later w)
    float* cvec   = u_w + (size_t)RTOT * BIW;           // 512*12

    // 1. Qp = (query @ Wq + bq) / 8
    linear16<<<dim3(32, 24), 256, 0, stream>>>(query, DMODEL, 0, Wq, bq, qp_ctx, DMODEL, 0.125f);
    // 2. u[r,h,m], cvec[r,h]
    u_kernel<<<dim3(16, 12, 12), 256, 0, stream>>>(qp_ctx, Wk, bk, u_w, cvec);
    // 3. scores/softmax/w  (w overwrites u region; u staged to LDS before w writes)
    attn_core<<<512, 1024, 0, stream>>>(key, value, mask, u_w, cvec, u_w);
    // 4. ctx[r, h*64+cc] = w[r,h,:] @ Wv[:, h*64+cc] + bv
    linear16<<<dim3(32, 24), 256, 0, stream>>>(u_w, BIW, DMODEL, Wv, bv, qp_ctx, DMODEL, 1.0f);
    // 5. out = ctx @ Wo + bo
    linear16<<<dim3(32, 24), 256, 0, stream>>>(qp_ctx, DMODEL, 0, Wo, bo, out, DMODEL, 1.0f);
}

// Round 8
// 177.181 us; speedup vs baseline: 1.4646x; 1.3474x over previous
//
#include <hip/hip_runtime.h>

// Problem constants: B=8, L=64, D=768, H=12, d=64
#define DMODEL 768
#define NHEADS 12
#define RTOT   512           // B*L rows
#define BIW    9216          // NHEADS*DMODEL (per-(b,i) u/w row)

// ---------------------------------------------------------------------------
// 16x32-tile fp32 GEMM, register-double-buffered K chunks of 64.
// grid = (32, 24), 256 threads
// ---------------------------------------------------------------------------
__global__ __launch_bounds__(256) void linear16(
    const float* __restrict__ src, int ars, int scm,
    const float* __restrict__ W, const float* __restrict__ bias,
    float* __restrict__ dst, int drs, float scale)
{
    __shared__ float At[16][64];   // 4 KB
    __shared__ float Bt[64][32];   // 8 KB
    const int rt = blockIdx.x, ct = blockIdx.y, t = threadIdx.x;
    const int sk = ((ct * 32) >> 6) * scm;
    const int c  = t & 31;
    const int rg = t >> 5;             // 8 groups x 2 rows

    const int ar0 = t >> 4,          ak0 = t & 15;          // 1 float4 A
    const int bk0 = t >> 3,          bc0 = (t & 7) * 4;     // 2 float4 B
    const int bk1 = (t + 256) >> 3,  bc1 = ((t + 256) & 7) * 4;

    float4 va0, vb0, vb1;
    auto LD = [&](int kb) {
        va0 = *(const float4*)&src[(size_t)(rt * 16 + ar0) * ars + sk + kb * 64 + ak0 * 4];
        vb0 = *(const float4*)&W[(size_t)(kb * 64 + bk0) * DMODEL + ct * 32 + bc0];
        vb1 = *(const float4*)&W[(size_t)(kb * 64 + bk1) * DMODEL + ct * 32 + bc1];
    };

    LD(0);
    float acc[2] = {0.f, 0.f};

    for (int kb = 0; kb < 12; ++kb) {
        if (kb) __syncthreads();
        *(float4*)&At[ar0][ak0 * 4] = va0;
        *(float4*)&Bt[bk0][bc0] = vb0;
        *(float4*)&Bt[bk1][bc1] = vb1;
        __syncthreads();
        if (kb < 11) LD(kb + 1);
        #pragma unroll
        for (int kq = 0; kq < 16; ++kq) {
            float b0 = Bt[kq * 4 + 0][c], b1 = Bt[kq * 4 + 1][c];
            float b2 = Bt[kq * 4 + 2][c], b3 = Bt[kq * 4 + 3][c];
            #pragma unroll
            for (int i = 0; i < 2; ++i) {
                float4 a = *(const float4*)&At[rg * 2 + i][kq * 4];
                acc[i] += a.x * b0 + a.y * b1 + a.z * b2 + a.w * b3;
            }
        }
    }
    const float bb = bias[ct * 32 + c];
    #pragma unroll
    for (int i = 0; i < 2; ++i)
        dst[(size_t)(rt * 16 + rg * 2 + i) * drs + ct * 32 + c] = (acc[i] + bb) * scale;
}

// ---------------------------------------------------------------------------
// u[r, h, m] = sum_d Qp[r, h*64+d] * Wk[m, h*64+d];  cvec[r,h] = sum_d bk[h*64+d]*Qp[r,h*64+d]
// grid = (16, 12, 12), 256 threads
// ---------------------------------------------------------------------------
__global__ __launch_bounds__(256) void u_kernel(
    const float* __restrict__ qp, const float* __restrict__ Wk, const float* __restrict__ bk,
    float* __restrict__ u, float* __restrict__ cvec)
{
    __shared__ float Qt[32][64];    // 8 KB
    __shared__ float Bt[64][65];    // 16.25 KB (pad -> conflict-free b32 row reads)
    const int rt = blockIdx.x, mt = blockIdx.y, h = blockIdx.z, t = threadIdx.x;

    #pragma unroll
    for (int kk = 0; kk < 2; ++kk) {
        int i4 = t + kk * 256;
        int r = i4 >> 4, dq = i4 & 15;
        *(float4*)&Qt[r][dq * 4] =
            *(const float4*)&qp[(size_t)(rt * 32 + r) * DMODEL + h * 64 + dq * 4];
    }
    #pragma unroll
    for (int kk = 0; kk < 4; ++kk) {
        int i4 = t + kk * 256;
        int m = i4 >> 4, dq = i4 & 15;
        float4 v = *(const float4*)&Wk[(size_t)(mt * 64 + m) * DMODEL + h * 64 + dq * 4];
        Bt[m][dq * 4 + 0] = v.x; Bt[m][dq * 4 + 1] = v.y;
        Bt[m][dq * 4 + 2] = v.z; Bt[m][dq * 4 + 3] = v.w;
    }
    __syncthreads();

    const int c = t & 63, rg = t >> 6;
    float acc[8] = {0.f,0.f,0.f,0.f,0.f,0.f,0.f,0.f};
    #pragma unroll
    for (int dq = 0; dq < 16; ++dq) {
        float b0 = Bt[c][dq * 4 + 0], b1 = Bt[c][dq * 4 + 1];
        float b2 = Bt[c][dq * 4 + 2], b3 = Bt[c][dq * 4 + 3];
        #pragma unroll
        for (int i = 0; i < 8; ++i) {
            float4 a = *(const float4*)&Qt[rg * 8 + i][dq * 4];
            acc[i] += a.x * b0 + a.y * b1 + a.z * b2 + a.w * b3;
        }
    }
    #pragma unroll
    for (int i = 0; i < 8; ++i)
        u[(size_t)(rt * 32 + rg * 8 + i) * BIW + h * DMODEL + mt * 64 + c] = acc[i];

    if (mt == 0 && t < 32) {
        float s = 0.f;
        for (int d = 0; d < 64; ++d) s += bk[h * 64 + d] * Qt[t][d];
        cvec[(rt * 32 + t) * NHEADS + h] = s;
    }
}

// ---------------------------------------------------------------------------
// scores_k: grid (512 bi, 2 j-halves), 256 threads, NO LDS.
// Block (bi,jh): wave wv owns rows j = jh*32 + wv*8 + pass*2 + {0,1}, 4 passes.
// u read directly from global (L1/L2-resident, coalesced 1 KB wave-loads).
// Writes sc_out[bi][h][j] = (key[bi,j,:].u[bi,h,:] + cvec[bi,h]) * mask[bi,j].
// ---------------------------------------------------------------------------
__global__ __launch_bounds__(256) void scores_k(
    const float* __restrict__ key, const float* __restrict__ u,
    const float* __restrict__ cvec, const float* __restrict__ mask,
    float* __restrict__ sc_out)
{
    const int bi   = blockIdx.x;
    const int jh   = blockIdx.y;
    const int t    = threadIdx.x;
    const int lane = t & 63;
    const int wv   = t >> 6;              // wave 0..3
    const size_t kvb = (size_t)bi * 64 * DMODEL;
    const float* ub = u + (size_t)bi * BIW + lane * 4;

    #pragma unroll
    for (int pass = 0; pass < 4; ++pass) {
        const int j0 = jh * 32 + wv * 8 + pass * 2;
        float a[NHEADS][2];
        #pragma unroll
        for (int h = 0; h < NHEADS; ++h) { a[h][0] = 0.f; a[h][1] = 0.f; }

        const float* k0 = &key[kvb + (size_t)j0 * DMODEL + lane * 4];
        float4 kc[2], kn[2];
        kc[0] = *(const float4*)k0;
        kc[1] = *(const float4*)(k0 + DMODEL);

        #pragma unroll
        for (int cch = 0; cch < 3; ++cch) {
            if (cch < 2) {
                kn[0] = *(const float4*)(k0 + (cch + 1) * 256);
                kn[1] = *(const float4*)(k0 + DMODEL + (cch + 1) * 256);
            }
            #pragma unroll
            for (int h = 0; h < NHEADS; ++h) {
                float4 u4 = *(const float4*)(ub + h * DMODEL + cch * 256);
                a[h][0] += kc[0].x * u4.x + kc[0].y * u4.y + kc[0].z * u4.z + kc[0].w * u4.w;
                a[h][1] += kc[1].x * u4.x + kc[1].y * u4.y + kc[1].z * u4.z + kc[1].w * u4.w;
            }
            kc[0] = kn[0];
            kc[1] = kn[1];
        }

        // split-tree reduce: 12 heads over 64 lanes
        #pragma unroll
        for (int r = 0; r < 2; ++r) {
            float s6[6];
            #pragma unroll
            for (int i = 0; i < 6; ++i) {
                float lo = a[i][r], hi = a[i + 6][r];
                float tl = __shfl_xor(lo, 32), th = __shfl_xor(hi, 32);
                s6[i] = (lane < 32) ? lo + tl : hi + th;
            }
            float s3[3];
            #pragma unroll
            for (int i = 0; i < 3; ++i) {
                float lo = s6[i], hi = s6[i + 3];
                float tl = __shfl_xor(lo, 16), th = __shfl_xor(hi, 16);
                s3[i] = ((lane & 16) == 0) ? lo + tl : hi + th;
            }
            #pragma unroll
            for (int o = 8; o >= 1; o >>= 1)
                #pragma unroll
                for (int i = 0; i < 3; ++i) s3[i] += __shfl_xor(s3[i], o);
            if ((lane & 15) == 0) {
                const int g = lane >> 4;
                const int j = j0 + r;
                const float mk = mask[bi * 64 + j];
                #pragma unroll
                for (int i = 0; i < 3; ++i) {
                    const int h = g * 3 + i;
                    sc_out[(size_t)bi * 768 + h * 64 + j] =
                        (s3[i] + cvec[bi * NHEADS + h]) * mk;
                }
            }
        }
    }
}

// ---------------------------------------------------------------------------
// pv_k: grid (512 bi, 3 m-chunks), 256 threads, 3 KB LDS.
// Softmax per head (wave wv -> heads wv*3..+3), then w[h][m] = sum_j attn*value.
// ---------------------------------------------------------------------------
__global__ __launch_bounds__(256) void pv_k(
    const float* __restrict__ value, const float* __restrict__ sc,
    float* __restrict__ w)
{
    __shared__ float attn[NHEADS][64];    // 3 KB

    const int bi   = blockIdx.x;
    const int ms   = blockIdx.y;
    const int t    = threadIdx.x;
    const int lane = t & 63;
    const int wv   = t >> 6;              // wave 0..3
    const size_t kvb = (size_t)bi * 64 * DMODEL;

    // softmax: wave wv handles heads wv*3 .. wv*3+2 (scores already masked+biased)
    #pragma unroll
    for (int i = 0; i < 3; ++i) {
        const int h = wv * 3 + i;
        float s = sc[(size_t)bi * 768 + h * 64 + lane];
        float mx = s;
        #pragma unroll
        for (int o = 1; o < 64; o <<= 1) mx = fmaxf(mx, __shfl_xor(mx, o));
        float e = __expf(s - mx);
        float sm = e;
        #pragma unroll
        for (int o = 1; o < 64; o <<= 1) sm += __shfl_xor(sm, o);
        attn[h][lane] = e / sm;
    }
    __syncthreads();

    // PV: thread owns column m = ms*256 + t
    const int mo = ms * 256 + t;
    float acc[NHEADS];
    #pragma unroll
    for (int h = 0; h < NHEADS; ++h) acc[h] = 0.f;
    const float* vb = value + kvb + mo;

    #pragma unroll 2
    for (int j4 = 0; j4 < 64; j4 += 4) {
        float v0 = vb[(size_t)(j4 + 0) * DMODEL];
        float v1 = vb[(size_t)(j4 + 1) * DMODEL];
        float v2 = vb[(size_t)(j4 + 2) * DMODEL];
        float v3 = vb[(size_t)(j4 + 3) * DMODEL];
        #pragma unroll
        for (int h = 0; h < NHEADS; ++h) {
            float4 at = *(const float4*)&attn[h][j4];   // lane-uniform -> LDS broadcast
            acc[h] += at.x * v0 + at.y * v1 + at.z * v2 + at.w * v3;
        }
    }
    #pragma unroll
    for (int h = 0; h < NHEADS; ++h)
        w[(size_t)bi * BIW + h * DMODEL + mo] = acc[h];
}

// ---------------------------------------------------------------------------
extern "C" void kernel_launch(void* const* d_in, const int* in_sizes, int n_in,
                              void* d_out, int out_size, void* d_ws, size_t ws_size,
                              hipStream_t stream) {
    const float* key   = (const float*)d_in[0];
    const float* value = (const float*)d_in[1];
    const float* query = (const float*)d_in[2];
    const float* mask  = (const float*)d_in[3];
    const float* Wk    = (const float*)d_in[4];
    const float* bk    = (const float*)d_in[5];
    const float* Wv    = (const float*)d_in[6];
    const float* bv    = (const float*)d_in[7];
    const float* Wq    = (const float*)d_in[8];
    const float* bq    = (const float*)d_in[9];
    const float* Wo    = (const float*)d_in[10];
    const float* bo    = (const float*)d_in[11];
    float* out = (float*)d_out;

    float* wsf    = (float*)d_ws;
    float* qp_ctx = wsf;                                // 512*768 (Qp, later ctx)
    float* u_w    = wsf + (size_t)RTOT * DMODEL;        // 512*9216 (u, later w)
    float* cvec   = u_w + (size_t)RTOT * BIW;           // 512*12
    float* sc_ws  = cvec + (size_t)RTOT * NHEADS;       // 512*768 scores

    // 1. Qp = (query @ Wq + bq) / 8
    linear16<<<dim3(32, 24), 256, 0, stream>>>(query, DMODEL, 0, Wq, bq, qp_ctx, DMODEL, 0.125f);
    // 2. u[r,h,m], cvec[r,h]
    u_kernel<<<dim3(16, 12, 12), 256, 0, stream>>>(qp_ctx, Wk, bk, u_w, cvec);
    // 3a. masked scores
    scores_k<<<dim3(512, 2), 256, 0, stream>>>(key, u_w, cvec, mask, sc_ws);
    // 3b. softmax + PV (w overwrites u region; kernel boundary orders the reuse)
    pv_k<<<dim3(512, 3), 256, 0, stream>>>(value, sc_ws, u_w);
    // 4. ctx[r, h*64+cc] = w[r,h,:] @ Wv[:, h*64+cc] + bv
    linear16<<<dim3(32, 24), 256, 0, stream>>>(u_w, BIW, DMODEL, Wv, bv, qp_ctx, DMODEL, 1.0f);
    // 5. out = ctx @ Wo + bo
    linear16<<<dim3(32, 24), 256, 0, stream>>>(qp_ctx, DMODEL, 0, Wo, bo, out, DMODEL, 1.0f);
}

// Round 9
// 161.170 us; speedup vs baseline: 1.6100x; 1.0993x over previous
//
#include <hip/hip_runtime.h>

// Problem constants: B=8, L=64, D=768, H=12, d=64
#define DMODEL 768
#define NHEADS 12
#define RTOT   512           // B*L rows
#define BIW    9216          // NHEADS*DMODEL (per-(b,i) u/w row)

// ---------------------------------------------------------------------------
// 16x32-tile fp32 GEMM, register-double-buffered K chunks of 64.
// grid = (32, 24), 256 threads
// ---------------------------------------------------------------------------
__global__ __launch_bounds__(256) void linear16(
    const float* __restrict__ src, int ars, int scm,
    const float* __restrict__ W, const float* __restrict__ bias,
    float* __restrict__ dst, int drs, float scale)
{
    __shared__ float At[16][64];   // 4 KB
    __shared__ float Bt[64][32];   // 8 KB
    const int rt = blockIdx.x, ct = blockIdx.y, t = threadIdx.x;
    const int sk = ((ct * 32) >> 6) * scm;
    const int c  = t & 31;
    const int rg = t >> 5;             // 8 groups x 2 rows

    const int ar0 = t >> 4,          ak0 = t & 15;          // 1 float4 A
    const int bk0 = t >> 3,          bc0 = (t & 7) * 4;     // 2 float4 B
    const int bk1 = (t + 256) >> 3,  bc1 = ((t + 256) & 7) * 4;

    float4 va0, vb0, vb1;
    auto LD = [&](int kb) {
        va0 = *(const float4*)&src[(size_t)(rt * 16 + ar0) * ars + sk + kb * 64 + ak0 * 4];
        vb0 = *(const float4*)&W[(size_t)(kb * 64 + bk0) * DMODEL + ct * 32 + bc0];
        vb1 = *(const float4*)&W[(size_t)(kb * 64 + bk1) * DMODEL + ct * 32 + bc1];
    };

    LD(0);
    float acc[2] = {0.f, 0.f};

    for (int kb = 0; kb < 12; ++kb) {
        if (kb) __syncthreads();
        *(float4*)&At[ar0][ak0 * 4] = va0;
        *(float4*)&Bt[bk0][bc0] = vb0;
        *(float4*)&Bt[bk1][bc1] = vb1;
        __syncthreads();
        if (kb < 11) LD(kb + 1);
        #pragma unroll
        for (int kq = 0; kq < 16; ++kq) {
            float b0 = Bt[kq * 4 + 0][c], b1 = Bt[kq * 4 + 1][c];
            float b2 = Bt[kq * 4 + 2][c], b3 = Bt[kq * 4 + 3][c];
            #pragma unroll
            for (int i = 0; i < 2; ++i) {
                float4 a = *(const float4*)&At[rg * 2 + i][kq * 4];
                acc[i] += a.x * b0 + a.y * b1 + a.z * b2 + a.w * b3;
            }
        }
    }
    const float bb = bias[ct * 32 + c];
    #pragma unroll
    for (int i = 0; i < 2; ++i)
        dst[(size_t)(rt * 16 + rg * 2 + i) * drs + ct * 32 + c] = (acc[i] + bb) * scale;
}

// ---------------------------------------------------------------------------
// u[r, h, m] = sum_d Qp[r, h*64+d] * Wk[m, h*64+d];  cvec[r,h] = sum_d bk[h*64+d]*Qp[r,h*64+d]
// grid = (16, 12, 12), 256 threads
// ---------------------------------------------------------------------------
__global__ __launch_bounds__(256) void u_kernel(
    const float* __restrict__ qp, const float* __restrict__ Wk, const float* __restrict__ bk,
    float* __restrict__ u, float* __restrict__ cvec)
{
    __shared__ float Qt[32][64];    // 8 KB
    __shared__ float Bt[64][65];    // 16.25 KB (pad -> conflict-free b32 row reads)
    const int rt = blockIdx.x, mt = blockIdx.y, h = blockIdx.z, t = threadIdx.x;

    #pragma unroll
    for (int kk = 0; kk < 2; ++kk) {
        int i4 = t + kk * 256;
        int r = i4 >> 4, dq = i4 & 15;
        *(float4*)&Qt[r][dq * 4] =
            *(const float4*)&qp[(size_t)(rt * 32 + r) * DMODEL + h * 64 + dq * 4];
    }
    #pragma unroll
    for (int kk = 0; kk < 4; ++kk) {
        int i4 = t + kk * 256;
        int m = i4 >> 4, dq = i4 & 15;
        float4 v = *(const float4*)&Wk[(size_t)(mt * 64 + m) * DMODEL + h * 64 + dq * 4];
        Bt[m][dq * 4 + 0] = v.x; Bt[m][dq * 4 + 1] = v.y;
        Bt[m][dq * 4 + 2] = v.z; Bt[m][dq * 4 + 3] = v.w;
    }
    __syncthreads();

    const int c = t & 63, rg = t >> 6;
    float acc[8] = {0.f,0.f,0.f,0.f,0.f,0.f,0.f,0.f};
    #pragma unroll
    for (int dq = 0; dq < 16; ++dq) {
        float b0 = Bt[c][dq * 4 + 0], b1 = Bt[c][dq * 4 + 1];
        float b2 = Bt[c][dq * 4 + 2], b3 = Bt[c][dq * 4 + 3];
        #pragma unroll
        for (int i = 0; i < 8; ++i) {
            float4 a = *(const float4*)&Qt[rg * 8 + i][dq * 4];
            acc[i] += a.x * b0 + a.y * b1 + a.z * b2 + a.w * b3;
        }
    }
    #pragma unroll
    for (int i = 0; i < 8; ++i)
        u[(size_t)(rt * 32 + rg * 8 + i) * BIW + h * DMODEL + mt * 64 + c] = acc[i];

    if (mt == 0 && t < 32) {
        float s = 0.f;
        for (int d = 0; d < 64; ++d) s += bk[h * 64 + d] * Qt[t][d];
        cvec[(rt * 32 + t) * NHEADS + h] = s;
    }
}

// ---------------------------------------------------------------------------
// scores_k v2: u RESIDENT IN REGISTERS, key streamed.
// grid (512 bi, 2 row-halves), 256 threads (4 waves).
// Wave wv owns heads wv*3..+3: u-frag = 9 float4/lane, loaded once.
// Loop 8 batches x 4 rows: 12 indep key loads, 36 FMA4, 30-shfl split-tree
// (12 values: rows pair across xor32, then xor16 -> quarter q owns row j0+q).
// ---------------------------------------------------------------------------
__global__ __launch_bounds__(256, 4) void scores_k(
    const float* __restrict__ key, const float* __restrict__ u,
    const float* __restrict__ cvec, const float* __restrict__ mask,
    float* __restrict__ sc_out)
{
    const int bi   = blockIdx.x;
    const int jh   = blockIdx.y;
    const int t    = threadIdx.x;
    const int lane = t & 63;
    const int wv   = t >> 6;              // wave 0..3
    const int h0   = wv * 3;
    const size_t kvb = (size_t)bi * 64 * DMODEL;

    // resident u fragments uf[i][cch]: u[bi, h0+i, cch*256 + lane*4 ..+4]
    float4 uf[3][3];
    #pragma unroll
    for (int i = 0; i < 3; ++i)
        #pragma unroll
        for (int cch = 0; cch < 3; ++cch)
            uf[i][cch] = *(const float4*)&u[(size_t)bi * BIW + (h0 + i) * DMODEL + cch * 256 + lane * 4];

    const float cv0 = cvec[bi * NHEADS + h0 + 0];
    const float cv1 = cvec[bi * NHEADS + h0 + 1];
    const float cv2 = cvec[bi * NHEADS + h0 + 2];

    #pragma unroll 1
    for (int b = 0; b < 8; ++b) {
        const int j0 = jh * 32 + b * 4;
        const float* kp = &key[kvb + (size_t)j0 * DMODEL + lane * 4];

        float4 k4[4][3];
        #pragma unroll
        for (int r = 0; r < 4; ++r)
            #pragma unroll
            for (int cch = 0; cch < 3; ++cch)
                k4[r][cch] = *(const float4*)(kp + (size_t)r * DMODEL + cch * 256);

        float v[3][4];
        #pragma unroll
        for (int i = 0; i < 3; ++i)
            #pragma unroll
            for (int r = 0; r < 4; ++r) v[i][r] = 0.f;

        #pragma unroll
        for (int cch = 0; cch < 3; ++cch)
            #pragma unroll
            for (int i = 0; i < 3; ++i) {
                const float4 uu = uf[i][cch];
                #pragma unroll
                for (int r = 0; r < 4; ++r)
                    v[i][r] += k4[r][cch].x * uu.x + k4[r][cch].y * uu.y
                             + k4[r][cch].z * uu.z + k4[r][cch].w * uu.w;
            }

        // reduce 12 values over 64 lanes
        float s[3][2];
        #pragma unroll
        for (int i = 0; i < 3; ++i)
            #pragma unroll
            for (int r = 0; r < 2; ++r) {
                float lo = v[i][r], hi = v[i][r + 2];
                float tl = __shfl_xor(lo, 32), th = __shfl_xor(hi, 32);
                s[i][r] = (lane < 32) ? lo + tl : hi + th;
            }
        float tt[3];
        #pragma unroll
        for (int i = 0; i < 3; ++i) {
            float lo = s[i][0], hi = s[i][1];
            float tl = __shfl_xor(lo, 16), th = __shfl_xor(hi, 16);
            tt[i] = ((lane & 16) == 0) ? lo + tl : hi + th;
        }
        #pragma unroll
        for (int o = 8; o >= 1; o >>= 1)
            #pragma unroll
            for (int i = 0; i < 3; ++i) tt[i] += __shfl_xor(tt[i], o);

        if ((lane & 15) == 0) {
            const int q = lane >> 4;          // quarter -> row j0+q
            const int j = j0 + q;
            const float mk = mask[bi * 64 + j];
            sc_out[(size_t)bi * 768 + (h0 + 0) * 64 + j] = (tt[0] + cv0) * mk;
            sc_out[(size_t)bi * 768 + (h0 + 1) * 64 + j] = (tt[1] + cv1) * mk;
            sc_out[(size_t)bi * 768 + (h0 + 2) * 64 + j] = (tt[2] + cv2) * mk;
        }
    }
}

// ---------------------------------------------------------------------------
// pv_k: grid (512 bi, 3 m-chunks), 256 threads, 3 KB LDS.
// Softmax per head (wave wv -> heads wv*3..+3), then w[h][m] = sum_j attn*value.
// ---------------------------------------------------------------------------
__global__ __launch_bounds__(256) void pv_k(
    const float* __restrict__ value, const float* __restrict__ sc,
    float* __restrict__ w)
{
    __shared__ float attn[NHEADS][64];    // 3 KB

    const int bi   = blockIdx.x;
    const int ms   = blockIdx.y;
    const int t    = threadIdx.x;
    const int lane = t & 63;
    const int wv   = t >> 6;              // wave 0..3
    const size_t kvb = (size_t)bi * 64 * DMODEL;

    // softmax: wave wv handles heads wv*3 .. wv*3+2 (scores already masked+biased)
    #pragma unroll
    for (int i = 0; i < 3; ++i) {
        const int h = wv * 3 + i;
        float s = sc[(size_t)bi * 768 + h * 64 + lane];
        float mx = s;
        #pragma unroll
        for (int o = 1; o < 64; o <<= 1) mx = fmaxf(mx, __shfl_xor(mx, o));
        float e = __expf(s - mx);
        float sm = e;
        #pragma unroll
        for (int o = 1; o < 64; o <<= 1) sm += __shfl_xor(sm, o);
        attn[h][lane] = e / sm;
    }
    __syncthreads();

    // PV: thread owns column m = ms*256 + t
    const int mo = ms * 256 + t;
    float acc[NHEADS];
    #pragma unroll
    for (int h = 0; h < NHEADS; ++h) acc[h] = 0.f;
    const float* vb = value + kvb + mo;

    #pragma unroll 2
    for (int j4 = 0; j4 < 64; j4 += 4) {
        float v0 = vb[(size_t)(j4 + 0) * DMODEL];
        float v1 = vb[(size_t)(j4 + 1) * DMODEL];
        float v2 = vb[(size_t)(j4 + 2) * DMODEL];
        float v3 = vb[(size_t)(j4 + 3) * DMODEL];
        #pragma unroll
        for (int h = 0; h < NHEADS; ++h) {
            float4 at = *(const float4*)&attn[h][j4];   // lane-uniform -> LDS broadcast
            acc[h] += at.x * v0 + at.y * v1 + at.z * v2 + at.w * v3;
        }
    }
    #pragma unroll
    for (int h = 0; h < NHEADS; ++h)
        w[(size_t)bi * BIW + h * DMODEL + mo] = acc[h];
}

// ---------------------------------------------------------------------------
extern "C" void kernel_launch(void* const* d_in, const int* in_sizes, int n_in,
                              void* d_out, int out_size, void* d_ws, size_t ws_size,
                              hipStream_t stream) {
    const float* key   = (const float*)d_in[0];
    const float* value = (const float*)d_in[1];
    const float* query = (const float*)d_in[2];
    const float* mask  = (const float*)d_in[3];
    const float* Wk    = (const float*)d_in[4];
    const float* bk    = (const float*)d_in[5];
    const float* Wv    = (const float*)d_in[6];
    const float* bv    = (const float*)d_in[7];
    const float* Wq    = (const float*)d_in[8];
    const float* bq    = (const float*)d_in[9];
    const float* Wo    = (const float*)d_in[10];
    const float* bo    = (const float*)d_in[11];
    float* out = (float*)d_out;

    float* wsf    = (float*)d_ws;
    float* qp_ctx = wsf;                                // 512*768 (Qp, later ctx)
    float* u_w    = wsf + (size_t)RTOT * DMODEL;        // 512*9216 (u, later w)
    float* cvec   = u_w + (size_t)RTOT * BIW;           // 512*12
    float* sc_ws  = cvec + (size_t)RTOT * NHEADS;       // 512*768 scores

    // 1. Qp = (query @ Wq + bq) / 8
    linear16<<<dim3(32, 24), 256, 0, stream>>>(query, DMODEL, 0, Wq, bq, qp_ctx, DMODEL, 0.125f);
    // 2. u[r,h,m], cvec[r,h]
    u_kernel<<<dim3(16, 12, 12), 256, 0, stream>>>(qp_ctx, Wk, bk, u_w, cvec);
    // 3a. masked scores
    scores_k<<<dim3(512, 2), 256, 0, stream>>>(key, u_w, cvec, mask, sc_ws);
    // 3b. softmax + PV (w overwrites u region; kernel boundary orders the reuse)
    pv_k<<<dim3(512, 3), 256, 0, stream>>>(value, sc_ws, u_w);
    // 4. ctx[r, h*64+cc] = w[r,h,:] @ Wv[:, h*64+cc] + bv
    linear16<<<dim3(32, 24), 256, 0, stream>>>(u_w, BIW, DMODEL, Wv, bv, qp_ctx, DMODEL, 1.0f);
    // 5. out = ctx @ Wo + bo
    linear16<<<dim3(32, 24), 256, 0, stream>>>(qp_ctx, DMODEL, 0, Wo, bo, out, DMODEL, 1.0f);
}